// Round 2
// baseline (680.711 us; speedup 1.0000x reference)
//
#include <hip/hip_runtime.h>

#define T_TOK 4096
#define HD 2048
#define NE 8
#define NI 1408

typedef __bf16 bf16x8 __attribute__((ext_vector_type(8)));
typedef float f32x4 __attribute__((ext_vector_type(4)));

#define S_WAITCNT_VMCNT(n) asm volatile("s_waitcnt vmcnt(" #n ")" ::: "memory")
__device__ __forceinline__ void wave_barrier() {
  asm volatile("" ::: "memory");
  __builtin_amdgcn_s_barrier();
  asm volatile("" ::: "memory");
}

__device__ __forceinline__ unsigned short f2bf(float f) {
  unsigned int u = __float_as_uint(f);
  u += 0x7FFFu + ((u >> 16) & 1u);
  return (unsigned short)(u >> 16);
}

__device__ __forceinline__ void gload_lds16(const void* g, void* l) {
  __builtin_amdgcn_global_load_lds(
      (const __attribute__((address_space(1))) unsigned int*)g,
      (__attribute__((address_space(3))) unsigned int*)l, 16, 0, 0);
}

// src [E][R][C] f32 -> dst [E][C][R] bf16.  Tile 64(r) x 32(c), 256 threads.
__global__ void transpose_cvt_kernel(const float* __restrict__ src,
                                     unsigned short* __restrict__ dst,
                                     int R, int C) {
  __shared__ float tile[64][33];
  int e = blockIdx.z;
  int c0 = blockIdx.x * 32, r0 = blockIdx.y * 64;
  int tid = threadIdx.x;
  int tx = tid & 31, rr = tid >> 5;
  const float* s = src + (size_t)e * R * C;
  unsigned short* d = dst + (size_t)e * R * C;
#pragma unroll
  for (int j = 0; j < 8; j++) {
    int r = rr + j * 8;
    tile[r][tx] = s[(size_t)(r0 + r) * C + c0 + tx];
  }
  __syncthreads();
  int l32 = tid & 31, cb = tid >> 5;
#pragma unroll
  for (int j = 0; j < 4; j++) {
    int c = cb + j * 8;
    ushort2 v = { f2bf(tile[2 * l32][c]), f2bf(tile[2 * l32 + 1][c]) };
    ((ushort2*)(d + (size_t)(c0 + c) * R + r0))[l32] = v;
  }
}

// ---------------- routing (also emits x in bf16) ----------------
__global__ void router_kernel(const float* __restrict__ x,
                              const float* __restrict__ Wr,
                              float* __restrict__ logits,
                              unsigned short* __restrict__ xbf,
                              int4* __restrict__ tokinfo,
                              int* __restrict__ cnt) {
  int wv = threadIdx.x >> 6, lane = threadIdx.x & 63;
  int t = blockIdx.x * 4 + wv;
  const float* xr = x + (size_t)t * HD;
  unsigned short* xbr = xbf + (size_t)t * HD;
  float acc[NE];
#pragma unroll
  for (int e = 0; e < NE; e++) acc[e] = 0.f;
  for (int hi = 0; hi < HD / 64; hi++) {
    int h = hi * 64 + lane;
    float xv = xr[h];
    xbr[h] = f2bf(xv);
    const float4* w4 = (const float4*)(Wr + (size_t)h * NE);
    float4 a = w4[0], b = w4[1];
    acc[0] += xv * a.x; acc[1] += xv * a.y; acc[2] += xv * a.z; acc[3] += xv * a.w;
    acc[4] += xv * b.x; acc[5] += xv * b.y; acc[6] += xv * b.z; acc[7] += xv * b.w;
  }
#pragma unroll
  for (int m = 32; m > 0; m >>= 1) {
#pragma unroll
    for (int e = 0; e < NE; e++) acc[e] += __shfl_xor(acc[e], m, 64);
  }
  if (lane < NE) logits[(size_t)t * NE + lane] = acc[lane];
  if (lane == 0) {
    int e0 = 0;
#pragma unroll
    for (int e = 1; e < NE; e++) if (acc[e] > acc[e0]) e0 = e;
    int e1 = (e0 == 0) ? 1 : 0;
#pragma unroll
    for (int e = 0; e < NE; e++) if (e != e0 && acc[e] > acc[e1]) e1 = e;
    float ex = expf(acc[e1] - acc[e0]);   // <= 1
    float w0 = 1.f / (1.f + ex);
    float w1 = ex / (1.f + ex);
    atomicAdd(&cnt[e0], 1);
    atomicAdd(&cnt[e1], 1);
    tokinfo[t] = make_int4(e0, e1, __float_as_int(w0), __float_as_int(w1));
  }
}

// cnt[0..7]=counts, cnt[8..15]=offsets, cnt[16..23]=scatter cursors
__global__ void offsets_kernel(int* __restrict__ cnt) {
  int o = 0;
  for (int e = 0; e < NE; e++) { cnt[8 + e] = o; o += cnt[e]; }
}

__global__ void scatter_kernel(const int4* __restrict__ tokinfo,
                               int* __restrict__ cnt,
                               int* __restrict__ row_tok,
                               float* __restrict__ row_w) {
  int t = blockIdx.x * blockDim.x + threadIdx.x;
  if (t >= T_TOK) return;
  int4 info = tokinfo[t];
  int p0 = atomicAdd(&cnt[16 + info.x], 1);
  int r0 = cnt[8 + info.x] + p0;
  row_tok[r0] = t; row_w[r0] = __int_as_float(info.z);
  int p1 = atomicAdd(&cnt[16 + info.y], 1);
  int r1 = cnt[8 + info.y] + p1;
  row_tok[r1] = t; row_w[r1] = __int_as_float(info.w);
}

// ---------------- grouped GEMM 1: act = silu(x@Wg) * (x@Wu) ----------------
// 128x128 tile, BK=32, 4 waves. Counted-vmcnt pipeline (raw s_barrier, no
// vmcnt(0) drain in steady state). XCD swizzle: expert = flat_id & 7.
__launch_bounds__(256, 3)
__global__ void gemm1_kernel(const unsigned short* __restrict__ xbf,
                             const unsigned short* __restrict__ Wgt,
                             const unsigned short* __restrict__ Wut,
                             unsigned short* __restrict__ act,
                             const int* __restrict__ row_tok,
                             const int* __restrict__ cnt) {
  // grid = dim3(11, 32, 8) flattened; remap so expert e -> XCD e, mt fastest.
  const int f = blockIdx.x + 11 * (blockIdx.y + 32 * blockIdx.z);
  const int e = f & 7;
  const int rem = f >> 3;          // 0..351
  const int nt = rem >> 5;         // 0..10
  const int mt = rem & 31;         // 0..31
  const int c = cnt[e];
  if (mt * 128 >= c) return;
  const int off = cnt[8 + e];
  const int rowbase = off + mt * 128, rowend = off + c;
  const int i0 = nt * 128;
  __shared__ __align__(16) char smem[49152];
  const int lane = threadIdx.x & 63, w = threadIdx.x >> 6;
  const int wr = w >> 1, wc = w & 1;

  const int rr0 = w * 16 + (lane >> 2);
  const int rr1 = rr0 + 64;
  const int q0 = (lane & 3) ^ ((rr0 >> 1) & 3);
  const int q1 = (lane & 3) ^ ((rr1 >> 1) & 3);
  int g0 = rowbase + rr0; if (g0 > rowend - 1) g0 = rowend - 1;
  int g1 = rowbase + rr1; if (g1 > rowend - 1) g1 = rowend - 1;
  const size_t tokA0 = (size_t)row_tok[g0] * HD;
  const size_t tokA1 = (size_t)row_tok[g1] * HD;
  const size_t bB0 = ((size_t)e * NI + i0 + rr0) * HD;
  const size_t bB1 = ((size_t)e * NI + i0 + rr1) * HD;
  const int ldsA = w * 1024;

  f32x4 zero = {0.f, 0.f, 0.f, 0.f};
  f32x4 accg[4][4], accu[4][4];
#pragma unroll
  for (int a = 0; a < 4; a++)
#pragma unroll
    for (int b = 0; b < 4; b++) { accg[a][b] = zero; accu[a][b] = zero; }

  auto stage = [&](int buf, int ks) {
    const int k0 = ks * 32;
    char* base = smem + buf * 24576;
    gload_lds16(xbf + tokA0 + k0 + q0 * 8, base + ldsA);
    gload_lds16(xbf + tokA1 + k0 + q1 * 8, base + ldsA + 4096);
    gload_lds16(Wgt + bB0 + k0 + q0 * 8, base + 8192 + ldsA);
    gload_lds16(Wgt + bB1 + k0 + q1 * 8, base + 8192 + ldsA + 4096);
    gload_lds16(Wut + bB0 + k0 + q0 * 8, base + 16384 + ldsA);
    gload_lds16(Wut + bB1 + k0 + q1 * 8, base + 16384 + ldsA + 4096);
  };
  const int rl = lane & 15, kslot = lane >> 4;
  auto compute = [&](int buf) {
    const char* base = smem + buf * 24576;
    bf16x8 af[4], bg[4], bu[4];
#pragma unroll
    for (int mi = 0; mi < 4; mi++) {
      int r = wr * 64 + mi * 16 + rl;
      int byt = r * 64 + ((kslot ^ ((r >> 1) & 3)) << 4);
      af[mi] = *(const bf16x8*)(base + byt);
    }
#pragma unroll
    for (int ni = 0; ni < 4; ni++) {
      int r = wc * 64 + ni * 16 + rl;
      int byt = r * 64 + ((kslot ^ ((r >> 1) & 3)) << 4);
      bg[ni] = *(const bf16x8*)(base + 8192 + byt);
      bu[ni] = *(const bf16x8*)(base + 16384 + byt);
    }
#pragma unroll
    for (int mi = 0; mi < 4; mi++)
#pragma unroll
      for (int ni = 0; ni < 4; ni++) {
        accg[mi][ni] = __builtin_amdgcn_mfma_f32_16x16x32_bf16(af[mi], bg[ni], accg[mi][ni], 0, 0, 0);
        accu[mi][ni] = __builtin_amdgcn_mfma_f32_16x16x32_bf16(af[mi], bu[ni], accu[mi][ni], 0, 0, 0);
      }
  };

  stage(0, 0);
  const int NKS = HD / 32;
  int ks = 0;
  for (; ks < NKS - 1; ks++) {
    stage((ks + 1) & 1, ks + 1);
    S_WAITCNT_VMCNT(6);      // wait for tile ks only; next tile stays in flight
    wave_barrier();
    compute(ks & 1);
    wave_barrier();
  }
  S_WAITCNT_VMCNT(0);
  wave_barrier();
  compute(ks & 1);

  const int rh = lane >> 4;
#pragma unroll
  for (int mi = 0; mi < 4; mi++)
#pragma unroll
    for (int ni = 0; ni < 4; ni++)
#pragma unroll
      for (int j = 0; j < 4; j++) {
        int grow = rowbase + wr * 64 + mi * 16 + rh * 4 + j;
        if (grow < rowend) {
          int gcol = i0 + wc * 64 + ni * 16 + rl;
          float g = accg[mi][ni][j], u = accu[mi][ni][j];
          float val = g / (1.f + __expf(-g)) * u;
          act[(size_t)grow * NI + gcol] = f2bf(val);
        }
      }
}

// ---------------- grouped GEMM 2: out[tok] += w * (act @ Wd) ----------------
__launch_bounds__(256, 4)
__global__ void gemm2_kernel(const unsigned short* __restrict__ act,
                             const unsigned short* __restrict__ Wdt,
                             float* __restrict__ out,
                             const int* __restrict__ row_tok,
                             const float* __restrict__ row_w,
                             const int* __restrict__ cnt) {
  // grid = dim3(16, 32, 8) flattened; expert e -> XCD e, mt fastest.
  const int f = blockIdx.x + 16 * (blockIdx.y + 32 * blockIdx.z);
  const int e = f & 7;
  const int rem = f >> 3;          // 0..511
  const int nt = rem >> 5;         // 0..15
  const int mt = rem & 31;         // 0..31
  const int c = cnt[e];
  if (mt * 128 >= c) return;
  const int off = cnt[8 + e];
  const int rowbase = off + mt * 128, rowend = off + c;
  const int n0 = nt * 128;
  __shared__ __align__(16) char smem[32768];
  const int lane = threadIdx.x & 63, w = threadIdx.x >> 6;
  const int wr = w >> 1, wc = w & 1;

  const int rr0 = w * 16 + (lane >> 2);
  const int rr1 = rr0 + 64;
  const int q0 = (lane & 3) ^ ((rr0 >> 1) & 3);
  const int q1 = (lane & 3) ^ ((rr1 >> 1) & 3);
  int g0 = rowbase + rr0; if (g0 > rowend - 1) g0 = rowend - 1;
  int g1 = rowbase + rr1; if (g1 > rowend - 1) g1 = rowend - 1;
  const size_t aA0 = (size_t)g0 * NI;
  const size_t aA1 = (size_t)g1 * NI;
  const size_t bB0 = ((size_t)e * HD + n0 + rr0) * NI;
  const size_t bB1 = ((size_t)e * HD + n0 + rr1) * NI;
  const int ldsA = w * 1024;

  f32x4 zero = {0.f, 0.f, 0.f, 0.f};
  f32x4 acc[4][4];
#pragma unroll
  for (int a = 0; a < 4; a++)
#pragma unroll
    for (int b = 0; b < 4; b++) acc[a][b] = zero;

  auto stage = [&](int buf, int ks) {
    const int k0 = ks * 32;
    char* base = smem + buf * 16384;
    gload_lds16(act + aA0 + k0 + q0 * 8, base + ldsA);
    gload_lds16(act + aA1 + k0 + q1 * 8, base + ldsA + 4096);
    gload_lds16(Wdt + bB0 + k0 + q0 * 8, base + 8192 + ldsA);
    gload_lds16(Wdt + bB1 + k0 + q1 * 8, base + 8192 + ldsA + 4096);
  };
  const int rl = lane & 15, kslot = lane >> 4;
  auto compute = [&](int buf) {
    const char* base = smem + buf * 16384;
    bf16x8 af[4], bf[4];
#pragma unroll
    for (int mi = 0; mi < 4; mi++) {
      int r = wr * 64 + mi * 16 + rl;
      int byt = r * 64 + ((kslot ^ ((r >> 1) & 3)) << 4);
      af[mi] = *(const bf16x8*)(base + byt);
    }
#pragma unroll
    for (int ni = 0; ni < 4; ni++) {
      int r = wc * 64 + ni * 16 + rl;
      int byt = r * 64 + ((kslot ^ ((r >> 1) & 3)) << 4);
      bf[ni] = *(const bf16x8*)(base + 8192 + byt);
    }
#pragma unroll
    for (int mi = 0; mi < 4; mi++)
#pragma unroll
      for (int ni = 0; ni < 4; ni++)
        acc[mi][ni] = __builtin_amdgcn_mfma_f32_16x16x32_bf16(af[mi], bf[ni], acc[mi][ni], 0, 0, 0);
  };

  stage(0, 0);
  const int NKS = NI / 32;
  int ks = 0;
  for (; ks < NKS - 1; ks++) {
    stage((ks + 1) & 1, ks + 1);
    S_WAITCNT_VMCNT(4);
    wave_barrier();
    compute(ks & 1);
    wave_barrier();
  }
  S_WAITCNT_VMCNT(0);
  wave_barrier();
  compute(ks & 1);

  const int rh = lane >> 4;
#pragma unroll
  for (int mi = 0; mi < 4; mi++)
#pragma unroll
    for (int ni = 0; ni < 4; ni++)
#pragma unroll
      for (int j = 0; j < 4; j++) {
        int grow = rowbase + wr * 64 + mi * 16 + rh * 4 + j;
        if (grow < rowend) {
          int t = row_tok[grow];
          float wgt = row_w[grow];
          int gcol = n0 + wc * 64 + ni * 16 + rl;
          unsafeAtomicAdd(&out[(size_t)t * HD + gcol], wgt * acc[mi][ni][j]);
        }
      }
}

// ---------------- launch ----------------
extern "C" void kernel_launch(void* const* d_in, const int* in_sizes, int n_in,
                              void* d_out, int out_size, void* d_ws, size_t ws_size,
                              hipStream_t stream) {
  const float* x  = (const float*)d_in[0];
  const float* Wr = (const float*)d_in[1];
  const float* Wg = (const float*)d_in[2];
  const float* Wu = (const float*)d_in[3];
  const float* Wd = (const float*)d_in[4];
  float* out = (float*)d_out;
  char* ws = (char*)d_ws;

  // ws layout (bytes)
  unsigned short* xbf = (unsigned short*)(ws);                 // 16,777,216
  unsigned short* Wgt = (unsigned short*)(ws + 16777216);      // 46,137,344
  unsigned short* Wut = (unsigned short*)(ws + 62914560);      // 46,137,344
  unsigned short* Wdt = (unsigned short*)(ws + 109051904);     // 46,137,344
  unsigned short* act = (unsigned short*)(ws + 155189248);     // 23,068,672
  int4*  tokinfo      = (int4*)(ws + 178257920);               // 65,536
  int*   row_tok      = (int*)(ws + 178323456);                // 32,768
  float* row_w        = (float*)(ws + 178356224);              // 32,768
  int*   cnt          = (int*)(ws + 178388992);                // 96

  hipMemsetAsync(out, 0, (size_t)T_TOK * HD * sizeof(float), stream);
  hipMemsetAsync(cnt, 0, 96, stream);

  router_kernel<<<T_TOK / 4, 256, 0, stream>>>(x, Wr, out + (size_t)T_TOK * HD, xbf, tokinfo, cnt);
  offsets_kernel<<<1, 1, 0, stream>>>(cnt);
  scatter_kernel<<<T_TOK / 256, 256, 0, stream>>>(tokinfo, cnt, row_tok, row_w);

  transpose_cvt_kernel<<<dim3(NI / 32, HD / 64, NE), 256, 0, stream>>>(Wg, Wgt, HD, NI);
  transpose_cvt_kernel<<<dim3(NI / 32, HD / 64, NE), 256, 0, stream>>>(Wu, Wut, HD, NI);
  transpose_cvt_kernel<<<dim3(HD / 32, NI / 64, NE), 256, 0, stream>>>(Wd, Wdt, NI, HD);

  gemm1_kernel<<<dim3(11, 32, NE), 256, 0, stream>>>(xbf, Wgt, Wut, act, row_tok, cnt);
  gemm2_kernel<<<dim3(16, 32, NE), 256, 0, stream>>>(act, Wdt, out, row_tok, row_w, cnt);
}

// Round 3
// 528.650 us; speedup vs baseline: 1.2876x; 1.2876x over previous
//
#include <hip/hip_runtime.h>

#define T_TOK 4096
#define HD 2048
#define NE 8
#define NI 1408

typedef __bf16 bf16x8 __attribute__((ext_vector_type(8)));
typedef float f32x4 __attribute__((ext_vector_type(4)));

#define S_WAITCNT_VMCNT(n) asm volatile("s_waitcnt vmcnt(" #n ")" ::: "memory")
__device__ __forceinline__ void wave_barrier() {
  asm volatile("" ::: "memory");
  __builtin_amdgcn_s_barrier();
  asm volatile("" ::: "memory");
}

__device__ __forceinline__ unsigned short f2bf(float f) {
  unsigned int u = __float_as_uint(f);
  u += 0x7FFFu + ((u >> 16) & 1u);
  return (unsigned short)(u >> 16);
}

__device__ __forceinline__ void gload_lds16(const void* g, void* l) {
  __builtin_amdgcn_global_load_lds(
      (const __attribute__((address_space(1))) unsigned int*)g,
      (__attribute__((address_space(3))) unsigned int*)l, 16, 0, 0);
}

// src [E][R][C] f32 -> dst [E][C][R] bf16.  Tile 64(r) x 32(c), 256 threads.
__global__ void transpose_cvt_kernel(const float* __restrict__ src,
                                     unsigned short* __restrict__ dst,
                                     int R, int C) {
  __shared__ float tile[64][33];
  int e = blockIdx.z;
  int c0 = blockIdx.x * 32, r0 = blockIdx.y * 64;
  int tid = threadIdx.x;
  int tx = tid & 31, rr = tid >> 5;
  const float* s = src + (size_t)e * R * C;
  unsigned short* d = dst + (size_t)e * R * C;
#pragma unroll
  for (int j = 0; j < 8; j++) {
    int r = rr + j * 8;
    tile[r][tx] = s[(size_t)(r0 + r) * C + c0 + tx];
  }
  __syncthreads();
  int l32 = tid & 31, cb = tid >> 5;
#pragma unroll
  for (int j = 0; j < 4; j++) {
    int c = cb + j * 8;
    ushort2 v = { f2bf(tile[2 * l32][c]), f2bf(tile[2 * l32 + 1][c]) };
    ((ushort2*)(d + (size_t)(c0 + c) * R + r0))[l32] = v;
  }
}

// ---------------- routing (also emits x in bf16) ----------------
__global__ void router_kernel(const float* __restrict__ x,
                              const float* __restrict__ Wr,
                              float* __restrict__ logits,
                              unsigned short* __restrict__ xbf,
                              int4* __restrict__ tokinfo,
                              int* __restrict__ cnt) {
  int wv = threadIdx.x >> 6, lane = threadIdx.x & 63;
  int t = blockIdx.x * 4 + wv;
  const float* xr = x + (size_t)t * HD;
  unsigned short* xbr = xbf + (size_t)t * HD;
  float acc[NE];
#pragma unroll
  for (int e = 0; e < NE; e++) acc[e] = 0.f;
  for (int hi = 0; hi < HD / 64; hi++) {
    int h = hi * 64 + lane;
    float xv = xr[h];
    xbr[h] = f2bf(xv);
    const float4* w4 = (const float4*)(Wr + (size_t)h * NE);
    float4 a = w4[0], b = w4[1];
    acc[0] += xv * a.x; acc[1] += xv * a.y; acc[2] += xv * a.z; acc[3] += xv * a.w;
    acc[4] += xv * b.x; acc[5] += xv * b.y; acc[6] += xv * b.z; acc[7] += xv * b.w;
  }
#pragma unroll
  for (int m = 32; m > 0; m >>= 1) {
#pragma unroll
    for (int e = 0; e < NE; e++) acc[e] += __shfl_xor(acc[e], m, 64);
  }
  if (lane < NE) logits[(size_t)t * NE + lane] = acc[lane];
  if (lane == 0) {
    int e0 = 0;
#pragma unroll
    for (int e = 1; e < NE; e++) if (acc[e] > acc[e0]) e0 = e;
    int e1 = (e0 == 0) ? 1 : 0;
#pragma unroll
    for (int e = 0; e < NE; e++) if (e != e0 && acc[e] > acc[e1]) e1 = e;
    float ex = expf(acc[e1] - acc[e0]);   // <= 1
    float w0 = 1.f / (1.f + ex);
    float w1 = ex / (1.f + ex);
    atomicAdd(&cnt[e0], 1);
    atomicAdd(&cnt[e1], 1);
    tokinfo[t] = make_int4(e0, e1, __float_as_int(w0), __float_as_int(w1));
  }
}

// cnt[0..7]=counts, cnt[8..15]=offsets, cnt[16..23]=scatter cursors
__global__ void offsets_kernel(int* __restrict__ cnt) {
  int o = 0;
  for (int e = 0; e < NE; e++) { cnt[8 + e] = o; o += cnt[e]; }
}

__global__ void scatter_kernel(const int4* __restrict__ tokinfo,
                               int* __restrict__ cnt,
                               int* __restrict__ row_tok,
                               float* __restrict__ row_w) {
  int t = blockIdx.x * blockDim.x + threadIdx.x;
  if (t >= T_TOK) return;
  int4 info = tokinfo[t];
  int p0 = atomicAdd(&cnt[16 + info.x], 1);
  int r0 = cnt[8 + info.x] + p0;
  row_tok[r0] = t; row_w[r0] = __int_as_float(info.z);
  int p1 = atomicAdd(&cnt[16 + info.y], 1);
  int r1 = cnt[8 + info.y] + p1;
  row_tok[r1] = t; row_w[r1] = __int_as_float(info.w);
}

// ---------------- grouped GEMM 1: act = silu(x@Wg) * (x@Wu) ----------------
// 128x128 tile, BK=32, 4 waves. Counted-vmcnt pipeline (raw s_barrier, no
// vmcnt(0) drain in steady state). XCD swizzle: expert = flat_id & 7.
// launch_bounds MUST stay (256,2): unified VGPR+AGPR file needs ~230 regs
// (128 accumulator + ~100 addr/frag); 3 waves/EU caps at 168 -> spills (R2).
__launch_bounds__(256, 2)
__global__ void gemm1_kernel(const unsigned short* __restrict__ xbf,
                             const unsigned short* __restrict__ Wgt,
                             const unsigned short* __restrict__ Wut,
                             unsigned short* __restrict__ act,
                             const int* __restrict__ row_tok,
                             const int* __restrict__ cnt) {
  // grid = dim3(11, 32, 8) flattened; remap so expert e -> XCD e, mt fastest.
  const int f = blockIdx.x + 11 * (blockIdx.y + 32 * blockIdx.z);
  const int e = f & 7;
  const int rem = f >> 3;          // 0..351
  const int nt = rem >> 5;         // 0..10
  const int mt = rem & 31;         // 0..31
  const int c = cnt[e];
  if (mt * 128 >= c) return;
  const int off = cnt[8 + e];
  const int rowbase = off + mt * 128, rowend = off + c;
  const int i0 = nt * 128;
  __shared__ __align__(16) char smem[49152];
  const int lane = threadIdx.x & 63, w = threadIdx.x >> 6;
  const int wr = w >> 1, wc = w & 1;

  const int rr0 = w * 16 + (lane >> 2);
  const int rr1 = rr0 + 64;
  const int q0 = (lane & 3) ^ ((rr0 >> 1) & 3);
  const int q1 = (lane & 3) ^ ((rr1 >> 1) & 3);
  int g0 = rowbase + rr0; if (g0 > rowend - 1) g0 = rowend - 1;
  int g1 = rowbase + rr1; if (g1 > rowend - 1) g1 = rowend - 1;
  const size_t tokA0 = (size_t)row_tok[g0] * HD;
  const size_t tokA1 = (size_t)row_tok[g1] * HD;
  const size_t bB0 = ((size_t)e * NI + i0 + rr0) * HD;
  const size_t bB1 = ((size_t)e * NI + i0 + rr1) * HD;
  const int ldsA = w * 1024;

  f32x4 zero = {0.f, 0.f, 0.f, 0.f};
  f32x4 accg[4][4], accu[4][4];
#pragma unroll
  for (int a = 0; a < 4; a++)
#pragma unroll
    for (int b = 0; b < 4; b++) { accg[a][b] = zero; accu[a][b] = zero; }

  auto stage = [&](int buf, int ks) {
    const int k0 = ks * 32;
    char* base = smem + buf * 24576;
    gload_lds16(xbf + tokA0 + k0 + q0 * 8, base + ldsA);
    gload_lds16(xbf + tokA1 + k0 + q1 * 8, base + ldsA + 4096);
    gload_lds16(Wgt + bB0 + k0 + q0 * 8, base + 8192 + ldsA);
    gload_lds16(Wgt + bB1 + k0 + q1 * 8, base + 8192 + ldsA + 4096);
    gload_lds16(Wut + bB0 + k0 + q0 * 8, base + 16384 + ldsA);
    gload_lds16(Wut + bB1 + k0 + q1 * 8, base + 16384 + ldsA + 4096);
  };
  const int rl = lane & 15, kslot = lane >> 4;
  auto compute = [&](int buf) {
    const char* base = smem + buf * 24576;
    bf16x8 af[4], bg[4], bu[4];
#pragma unroll
    for (int mi = 0; mi < 4; mi++) {
      int r = wr * 64 + mi * 16 + rl;
      int byt = r * 64 + ((kslot ^ ((r >> 1) & 3)) << 4);
      af[mi] = *(const bf16x8*)(base + byt);
    }
#pragma unroll
    for (int ni = 0; ni < 4; ni++) {
      int r = wc * 64 + ni * 16 + rl;
      int byt = r * 64 + ((kslot ^ ((r >> 1) & 3)) << 4);
      bg[ni] = *(const bf16x8*)(base + 8192 + byt);
      bu[ni] = *(const bf16x8*)(base + 16384 + byt);
    }
#pragma unroll
    for (int mi = 0; mi < 4; mi++)
#pragma unroll
      for (int ni = 0; ni < 4; ni++) {
        accg[mi][ni] = __builtin_amdgcn_mfma_f32_16x16x32_bf16(af[mi], bg[ni], accg[mi][ni], 0, 0, 0);
        accu[mi][ni] = __builtin_amdgcn_mfma_f32_16x16x32_bf16(af[mi], bu[ni], accu[mi][ni], 0, 0, 0);
      }
  };

  stage(0, 0);
  const int NKS = HD / 32;
  int ks = 0;
  for (; ks < NKS - 1; ks++) {
    stage((ks + 1) & 1, ks + 1);
    S_WAITCNT_VMCNT(6);      // wait for tile ks only; next tile stays in flight
    wave_barrier();
    compute(ks & 1);
    wave_barrier();
  }
  S_WAITCNT_VMCNT(0);
  wave_barrier();
  compute(ks & 1);

  const int rh = lane >> 4;
#pragma unroll
  for (int mi = 0; mi < 4; mi++)
#pragma unroll
    for (int ni = 0; ni < 4; ni++)
#pragma unroll
      for (int j = 0; j < 4; j++) {
        int grow = rowbase + wr * 64 + mi * 16 + rh * 4 + j;
        if (grow < rowend) {
          int gcol = i0 + wc * 64 + ni * 16 + rl;
          float g = accg[mi][ni][j], u = accu[mi][ni][j];
          float val = g / (1.f + __expf(-g)) * u;
          act[(size_t)grow * NI + gcol] = f2bf(val);
        }
      }
}

// ---------------- grouped GEMM 2: out[tok] += w * (act @ Wd) ----------------
// launch_bounds (256,2): 64 acc regs + frags + addr ~ 180 regs; 4/EU spilled (R2).
__launch_bounds__(256, 2)
__global__ void gemm2_kernel(const unsigned short* __restrict__ act,
                             const unsigned short* __restrict__ Wdt,
                             float* __restrict__ out,
                             const int* __restrict__ row_tok,
                             const float* __restrict__ row_w,
                             const int* __restrict__ cnt) {
  // grid = dim3(16, 32, 8) flattened; expert e -> XCD e, mt fastest.
  const int f = blockIdx.x + 16 * (blockIdx.y + 32 * blockIdx.z);
  const int e = f & 7;
  const int rem = f >> 3;          // 0..511
  const int nt = rem >> 5;         // 0..15
  const int mt = rem & 31;         // 0..31
  const int c = cnt[e];
  if (mt * 128 >= c) return;
  const int off = cnt[8 + e];
  const int rowbase = off + mt * 128, rowend = off + c;
  const int n0 = nt * 128;
  __shared__ __align__(16) char smem[32768];
  const int lane = threadIdx.x & 63, w = threadIdx.x >> 6;
  const int wr = w >> 1, wc = w & 1;

  const int rr0 = w * 16 + (lane >> 2);
  const int rr1 = rr0 + 64;
  const int q0 = (lane & 3) ^ ((rr0 >> 1) & 3);
  const int q1 = (lane & 3) ^ ((rr1 >> 1) & 3);
  int g0 = rowbase + rr0; if (g0 > rowend - 1) g0 = rowend - 1;
  int g1 = rowbase + rr1; if (g1 > rowend - 1) g1 = rowend - 1;
  const size_t aA0 = (size_t)g0 * NI;
  const size_t aA1 = (size_t)g1 * NI;
  const size_t bB0 = ((size_t)e * HD + n0 + rr0) * NI;
  const size_t bB1 = ((size_t)e * HD + n0 + rr1) * NI;
  const int ldsA = w * 1024;

  f32x4 zero = {0.f, 0.f, 0.f, 0.f};
  f32x4 acc[4][4];
#pragma unroll
  for (int a = 0; a < 4; a++)
#pragma unroll
    for (int b = 0; b < 4; b++) acc[a][b] = zero;

  auto stage = [&](int buf, int ks) {
    const int k0 = ks * 32;
    char* base = smem + buf * 16384;
    gload_lds16(act + aA0 + k0 + q0 * 8, base + ldsA);
    gload_lds16(act + aA1 + k0 + q1 * 8, base + ldsA + 4096);
    gload_lds16(Wdt + bB0 + k0 + q0 * 8, base + 8192 + ldsA);
    gload_lds16(Wdt + bB1 + k0 + q1 * 8, base + 8192 + ldsA + 4096);
  };
  const int rl = lane & 15, kslot = lane >> 4;
  auto compute = [&](int buf) {
    const char* base = smem + buf * 16384;
    bf16x8 af[4], bf[4];
#pragma unroll
    for (int mi = 0; mi < 4; mi++) {
      int r = wr * 64 + mi * 16 + rl;
      int byt = r * 64 + ((kslot ^ ((r >> 1) & 3)) << 4);
      af[mi] = *(const bf16x8*)(base + byt);
    }
#pragma unroll
    for (int ni = 0; ni < 4; ni++) {
      int r = wc * 64 + ni * 16 + rl;
      int byt = r * 64 + ((kslot ^ ((r >> 1) & 3)) << 4);
      bf[ni] = *(const bf16x8*)(base + 8192 + byt);
    }
#pragma unroll
    for (int mi = 0; mi < 4; mi++)
#pragma unroll
      for (int ni = 0; ni < 4; ni++)
        acc[mi][ni] = __builtin_amdgcn_mfma_f32_16x16x32_bf16(af[mi], bf[ni], acc[mi][ni], 0, 0, 0);
  };

  stage(0, 0);
  const int NKS = NI / 32;
  int ks = 0;
  for (; ks < NKS - 1; ks++) {
    stage((ks + 1) & 1, ks + 1);
    S_WAITCNT_VMCNT(4);
    wave_barrier();
    compute(ks & 1);
    wave_barrier();
  }
  S_WAITCNT_VMCNT(0);
  wave_barrier();
  compute(ks & 1);

  const int rh = lane >> 4;
#pragma unroll
  for (int mi = 0; mi < 4; mi++)
#pragma unroll
    for (int ni = 0; ni < 4; ni++)
#pragma unroll
      for (int j = 0; j < 4; j++) {
        int grow = rowbase + wr * 64 + mi * 16 + rh * 4 + j;
        if (grow < rowend) {
          int t = row_tok[grow];
          float wgt = row_w[grow];
          int gcol = n0 + wc * 64 + ni * 16 + rl;
          unsafeAtomicAdd(&out[(size_t)t * HD + gcol], wgt * acc[mi][ni][j]);
        }
      }
}

// ---------------- launch ----------------
extern "C" void kernel_launch(void* const* d_in, const int* in_sizes, int n_in,
                              void* d_out, int out_size, void* d_ws, size_t ws_size,
                              hipStream_t stream) {
  const float* x  = (const float*)d_in[0];
  const float* Wr = (const float*)d_in[1];
  const float* Wg = (const float*)d_in[2];
  const float* Wu = (const float*)d_in[3];
  const float* Wd = (const float*)d_in[4];
  float* out = (float*)d_out;
  char* ws = (char*)d_ws;

  // ws layout (bytes)
  unsigned short* xbf = (unsigned short*)(ws);                 // 16,777,216
  unsigned short* Wgt = (unsigned short*)(ws + 16777216);      // 46,137,344
  unsigned short* Wut = (unsigned short*)(ws + 62914560);      // 46,137,344
  unsigned short* Wdt = (unsigned short*)(ws + 109051904);     // 46,137,344
  unsigned short* act = (unsigned short*)(ws + 155189248);     // 23,068,672
  int4*  tokinfo      = (int4*)(ws + 178257920);               // 65,536
  int*   row_tok      = (int*)(ws + 178323456);                // 32,768
  float* row_w        = (float*)(ws + 178356224);              // 32,768
  int*   cnt          = (int*)(ws + 178388992);                // 96

  hipMemsetAsync(out, 0, (size_t)T_TOK * HD * sizeof(float), stream);
  hipMemsetAsync(cnt, 0, 96, stream);

  router_kernel<<<T_TOK / 4, 256, 0, stream>>>(x, Wr, out + (size_t)T_TOK * HD, xbf, tokinfo, cnt);
  offsets_kernel<<<1, 1, 0, stream>>>(cnt);
  scatter_kernel<<<T_TOK / 256, 256, 0, stream>>>(tokinfo, cnt, row_tok, row_w);

  transpose_cvt_kernel<<<dim3(NI / 32, HD / 64, NE), 256, 0, stream>>>(Wg, Wgt, HD, NI);
  transpose_cvt_kernel<<<dim3(NI / 32, HD / 64, NE), 256, 0, stream>>>(Wu, Wut, HD, NI);
  transpose_cvt_kernel<<<dim3(HD / 32, NI / 64, NE), 256, 0, stream>>>(Wd, Wdt, NI, HD);

  gemm1_kernel<<<dim3(11, 32, NE), 256, 0, stream>>>(xbf, Wgt, Wut, act, row_tok, cnt);
  gemm2_kernel<<<dim3(16, 32, NE), 256, 0, stream>>>(act, Wdt, out, row_tok, row_w, cnt);
}

// Round 4
// 459.916 us; speedup vs baseline: 1.4801x; 1.1494x over previous
//
#include <hip/hip_runtime.h>

#define T_TOK 4096
#define HD 2048
#define NE 8
#define NI 1408

typedef __bf16 bf16x8 __attribute__((ext_vector_type(8)));
typedef float f32x4 __attribute__((ext_vector_type(4)));
typedef unsigned short ushort8 __attribute__((ext_vector_type(8)));

#define S_WAITCNT_VMCNT(n) asm volatile("s_waitcnt vmcnt(" #n ")" ::: "memory")
__device__ __forceinline__ void wave_barrier() {
  asm volatile("" ::: "memory");
  __builtin_amdgcn_s_barrier();
  asm volatile("" ::: "memory");
}

__device__ __forceinline__ unsigned short f2bf(float f) {
  unsigned int u = __float_as_uint(f);
  u += 0x7FFFu + ((u >> 16) & 1u);
  return (unsigned short)(u >> 16);
}
__device__ __forceinline__ float bf2f(unsigned short u) {
  return __uint_as_float((unsigned int)u << 16);
}

__device__ __forceinline__ void gload_lds16(const void* g, void* l) {
  __builtin_amdgcn_global_load_lds(
      (const __attribute__((address_space(1))) unsigned int*)g,
      (__attribute__((address_space(3))) unsigned int*)l, 16, 0, 0);
}

// src [E][R][C] f32 -> dst [E][C][R] bf16.  64x64 tile, 256 threads.
// Loads: float4/lane. Stores: ushort8 (16B)/lane, 8 lanes cover one 128B
// output-row chunk. LDS [64][65]: both phases ~2-way banked (free).
__global__ void transpose_cvt_kernel(const float* __restrict__ src,
                                     unsigned short* __restrict__ dst,
                                     int R, int C) {
  __shared__ float tile[64][65];
  int e = blockIdx.z;
  int r0 = blockIdx.y * 64, c0 = blockIdx.x * 64;
  const float* s = src + (size_t)e * R * C;
  unsigned short* d = dst + (size_t)e * R * C;
  int tid = threadIdx.x;
  int lr = tid >> 4, lc = (tid & 15) * 4;
#pragma unroll
  for (int p = 0; p < 4; p++) {
    int r = lr + p * 16;
    float4 v = *(const float4*)(s + (size_t)(r0 + r) * C + c0 + lc);
    tile[r][lc] = v.x; tile[r][lc + 1] = v.y;
    tile[r][lc + 2] = v.z; tile[r][lc + 3] = v.w;
  }
  __syncthreads();
  int rbase = (tid & 7) * 8, crel = tid >> 3;   // crel 0..31
#pragma unroll
  for (int p = 0; p < 2; p++) {
    int c = p * 32 + crel;
    ushort8 o;
#pragma unroll
    for (int j = 0; j < 8; j++) o[j] = f2bf(tile[rbase + j][c]);
    *(ushort8*)(d + (size_t)(c0 + c) * R + r0 + rbase) = o;
  }
}

// ---------------- routing (also emits x in bf16) ----------------
__global__ void router_kernel(const float* __restrict__ x,
                              const float* __restrict__ Wr,
                              float* __restrict__ logits,
                              unsigned short* __restrict__ xbf,
                              int4* __restrict__ tokinfo,
                              int* __restrict__ cnt) {
  int wv = threadIdx.x >> 6, lane = threadIdx.x & 63;
  int t = blockIdx.x * 4 + wv;
  const float* xr = x + (size_t)t * HD;
  unsigned short* xbr = xbf + (size_t)t * HD;
  float acc[NE];
#pragma unroll
  for (int e = 0; e < NE; e++) acc[e] = 0.f;
  for (int hi = 0; hi < HD / 64; hi++) {
    int h = hi * 64 + lane;
    float xv = xr[h];
    xbr[h] = f2bf(xv);
    const float4* w4 = (const float4*)(Wr + (size_t)h * NE);
    float4 a = w4[0], b = w4[1];
    acc[0] += xv * a.x; acc[1] += xv * a.y; acc[2] += xv * a.z; acc[3] += xv * a.w;
    acc[4] += xv * b.x; acc[5] += xv * b.y; acc[6] += xv * b.z; acc[7] += xv * b.w;
  }
#pragma unroll
  for (int m = 32; m > 0; m >>= 1) {
#pragma unroll
    for (int e = 0; e < NE; e++) acc[e] += __shfl_xor(acc[e], m, 64);
  }
  if (lane < NE) logits[(size_t)t * NE + lane] = acc[lane];
  if (lane == 0) {
    int e0 = 0;
#pragma unroll
    for (int e = 1; e < NE; e++) if (acc[e] > acc[e0]) e0 = e;
    int e1 = (e0 == 0) ? 1 : 0;
#pragma unroll
    for (int e = 0; e < NE; e++) if (e != e0 && acc[e] > acc[e1]) e1 = e;
    float ex = expf(acc[e1] - acc[e0]);   // <= 1
    float w0 = 1.f / (1.f + ex);
    float w1 = ex / (1.f + ex);
    atomicAdd(&cnt[e0], 1);
    atomicAdd(&cnt[e1], 1);
    tokinfo[t] = make_int4(e0, e1, __float_as_int(w0), __float_as_int(w1));
  }
}

// cnt[0..7]=counts, cnt[8..15]=offsets, cnt[16..23]=scatter cursors
__global__ void offsets_kernel(int* __restrict__ cnt) {
  int o = 0;
  for (int e = 0; e < NE; e++) { cnt[8 + e] = o; o += cnt[e]; }
}

__global__ void scatter_kernel(const int4* __restrict__ tokinfo,
                               int* __restrict__ cnt,
                               int* __restrict__ row_tok,
                               int2* __restrict__ tok2row) {
  int t = blockIdx.x * blockDim.x + threadIdx.x;
  if (t >= T_TOK) return;
  int4 info = tokinfo[t];
  int p0 = atomicAdd(&cnt[16 + info.x], 1);
  int r0 = cnt[8 + info.x] + p0;
  row_tok[r0] = t;
  int p1 = atomicAdd(&cnt[16 + info.y], 1);
  int r1 = cnt[8 + info.y] + p1;
  row_tok[r1] = t;
  tok2row[t] = make_int2(r0, r1);
}

// ---------------- grouped GEMM 1: act = silu(x@Wg) * (x@Wu) ----------------
// 128x128 tile, BK=32, 4 waves. Counted-vmcnt pipeline (raw s_barrier, no
// vmcnt(0) drain in steady state). XCD swizzle: expert = flat_id & 7.
// launch_bounds MUST stay (256,2): 128 acc regs + ~100 VGPR; 3/EU spills (R2).
__launch_bounds__(256, 2)
__global__ void gemm1_kernel(const unsigned short* __restrict__ xbf,
                             const unsigned short* __restrict__ Wgt,
                             const unsigned short* __restrict__ Wut,
                             unsigned short* __restrict__ act,
                             const int* __restrict__ row_tok,
                             const int* __restrict__ cnt) {
  // grid = dim3(11, 32, 8) flattened; remap so expert e -> XCD e, mt fastest.
  const int f = blockIdx.x + 11 * (blockIdx.y + 32 * blockIdx.z);
  const int e = f & 7;
  const int rem = f >> 3;          // 0..351
  const int nt = rem >> 5;         // 0..10
  const int mt = rem & 31;         // 0..31
  const int c = cnt[e];
  if (mt * 128 >= c) return;
  const int off = cnt[8 + e];
  const int rowbase = off + mt * 128, rowend = off + c;
  const int i0 = nt * 128;
  __shared__ __align__(16) char smem[49152];
  const int lane = threadIdx.x & 63, w = threadIdx.x >> 6;
  const int wr = w >> 1, wc = w & 1;

  const int rr0 = w * 16 + (lane >> 2);
  const int rr1 = rr0 + 64;
  const int q0 = (lane & 3) ^ ((rr0 >> 1) & 3);
  const int q1 = (lane & 3) ^ ((rr1 >> 1) & 3);
  int g0 = rowbase + rr0; if (g0 > rowend - 1) g0 = rowend - 1;
  int g1 = rowbase + rr1; if (g1 > rowend - 1) g1 = rowend - 1;
  const size_t tokA0 = (size_t)row_tok[g0] * HD;
  const size_t tokA1 = (size_t)row_tok[g1] * HD;
  const size_t bB0 = ((size_t)e * NI + i0 + rr0) * HD;
  const size_t bB1 = ((size_t)e * NI + i0 + rr1) * HD;
  const int ldsA = w * 1024;

  f32x4 zero = {0.f, 0.f, 0.f, 0.f};
  f32x4 accg[4][4], accu[4][4];
#pragma unroll
  for (int a = 0; a < 4; a++)
#pragma unroll
    for (int b = 0; b < 4; b++) { accg[a][b] = zero; accu[a][b] = zero; }

  auto stage = [&](int buf, int ks) {
    const int k0 = ks * 32;
    char* base = smem + buf * 24576;
    gload_lds16(xbf + tokA0 + k0 + q0 * 8, base + ldsA);
    gload_lds16(xbf + tokA1 + k0 + q1 * 8, base + ldsA + 4096);
    gload_lds16(Wgt + bB0 + k0 + q0 * 8, base + 8192 + ldsA);
    gload_lds16(Wgt + bB1 + k0 + q1 * 8, base + 8192 + ldsA + 4096);
    gload_lds16(Wut + bB0 + k0 + q0 * 8, base + 16384 + ldsA);
    gload_lds16(Wut + bB1 + k0 + q1 * 8, base + 16384 + ldsA + 4096);
  };
  const int rl = lane & 15, kslot = lane >> 4;
  auto compute = [&](int buf) {
    const char* base = smem + buf * 24576;
    bf16x8 af[4], bg[4], bu[4];
#pragma unroll
    for (int mi = 0; mi < 4; mi++) {
      int r = wr * 64 + mi * 16 + rl;
      int byt = r * 64 + ((kslot ^ ((r >> 1) & 3)) << 4);
      af[mi] = *(const bf16x8*)(base + byt);
    }
#pragma unroll
    for (int ni = 0; ni < 4; ni++) {
      int r = wc * 64 + ni * 16 + rl;
      int byt = r * 64 + ((kslot ^ ((r >> 1) & 3)) << 4);
      bg[ni] = *(const bf16x8*)(base + 8192 + byt);
      bu[ni] = *(const bf16x8*)(base + 16384 + byt);
    }
#pragma unroll
    for (int mi = 0; mi < 4; mi++)
#pragma unroll
      for (int ni = 0; ni < 4; ni++) {
        accg[mi][ni] = __builtin_amdgcn_mfma_f32_16x16x32_bf16(af[mi], bg[ni], accg[mi][ni], 0, 0, 0);
        accu[mi][ni] = __builtin_amdgcn_mfma_f32_16x16x32_bf16(af[mi], bu[ni], accu[mi][ni], 0, 0, 0);
      }
  };

  stage(0, 0);
  const int NKS = HD / 32;
  int ks = 0;
  for (; ks < NKS - 1; ks++) {
    stage((ks + 1) & 1, ks + 1);
    S_WAITCNT_VMCNT(6);      // wait for tile ks only; next tile stays in flight
    wave_barrier();
    compute(ks & 1);
    wave_barrier();
  }
  S_WAITCNT_VMCNT(0);
  wave_barrier();
  compute(ks & 1);

  const int rh = lane >> 4;
#pragma unroll
  for (int mi = 0; mi < 4; mi++)
#pragma unroll
    for (int ni = 0; ni < 4; ni++)
#pragma unroll
      for (int j = 0; j < 4; j++) {
        int grow = rowbase + wr * 64 + mi * 16 + rh * 4 + j;
        if (grow < rowend) {
          int gcol = i0 + wc * 64 + ni * 16 + rl;
          float g = accg[mi][ni][j], u = accu[mi][ni][j];
          float val = g / (1.f + __expf(-g)) * u;
          act[(size_t)grow * NI + gcol] = f2bf(val);
        }
      }
}

// ---------------- grouped GEMM 2: y[row] = act[row] @ Wd  (no atomics) ------
__launch_bounds__(256, 3)
__global__ void gemm2_kernel(const unsigned short* __restrict__ act,
                             const unsigned short* __restrict__ Wdt,
                             unsigned short* __restrict__ y,
                             const int* __restrict__ cnt) {
  // grid = dim3(16, 32, 8) flattened; expert e -> XCD e, mt fastest.
  const int f = blockIdx.x + 16 * (blockIdx.y + 32 * blockIdx.z);
  const int e = f & 7;
  const int rem = f >> 3;          // 0..511
  const int nt = rem >> 5;         // 0..15
  const int mt = rem & 31;         // 0..31
  const int c = cnt[e];
  if (mt * 128 >= c) return;
  const int off = cnt[8 + e];
  const int rowbase = off + mt * 128, rowend = off + c;
  const int n0 = nt * 128;
  __shared__ __align__(16) char smem[32768];
  const int lane = threadIdx.x & 63, w = threadIdx.x >> 6;
  const int wr = w >> 1, wc = w & 1;

  const int rr0 = w * 16 + (lane >> 2);
  const int rr1 = rr0 + 64;
  const int q0 = (lane & 3) ^ ((rr0 >> 1) & 3);
  const int q1 = (lane & 3) ^ ((rr1 >> 1) & 3);
  int g0 = rowbase + rr0; if (g0 > rowend - 1) g0 = rowend - 1;
  int g1 = rowbase + rr1; if (g1 > rowend - 1) g1 = rowend - 1;
  const size_t aA0 = (size_t)g0 * NI;
  const size_t aA1 = (size_t)g1 * NI;
  const size_t bB0 = ((size_t)e * HD + n0 + rr0) * NI;
  const size_t bB1 = ((size_t)e * HD + n0 + rr1) * NI;
  const int ldsA = w * 1024;

  f32x4 zero = {0.f, 0.f, 0.f, 0.f};
  f32x4 acc[4][4];
#pragma unroll
  for (int a = 0; a < 4; a++)
#pragma unroll
    for (int b = 0; b < 4; b++) acc[a][b] = zero;

  auto stage = [&](int buf, int ks) {
    const int k0 = ks * 32;
    char* base = smem + buf * 16384;
    gload_lds16(act + aA0 + k0 + q0 * 8, base + ldsA);
    gload_lds16(act + aA1 + k0 + q1 * 8, base + ldsA + 4096);
    gload_lds16(Wdt + bB0 + k0 + q0 * 8, base + 8192 + ldsA);
    gload_lds16(Wdt + bB1 + k0 + q1 * 8, base + 8192 + ldsA + 4096);
  };
  const int rl = lane & 15, kslot = lane >> 4;
  auto compute = [&](int buf) {
    const char* base = smem + buf * 16384;
    bf16x8 af[4], bf[4];
#pragma unroll
    for (int mi = 0; mi < 4; mi++) {
      int r = wr * 64 + mi * 16 + rl;
      int byt = r * 64 + ((kslot ^ ((r >> 1) & 3)) << 4);
      af[mi] = *(const bf16x8*)(base + byt);
    }
#pragma unroll
    for (int ni = 0; ni < 4; ni++) {
      int r = wc * 64 + ni * 16 + rl;
      int byt = r * 64 + ((kslot ^ ((r >> 1) & 3)) << 4);
      bf[ni] = *(const bf16x8*)(base + 8192 + byt);
    }
#pragma unroll
    for (int mi = 0; mi < 4; mi++)
#pragma unroll
      for (int ni = 0; ni < 4; ni++)
        acc[mi][ni] = __builtin_amdgcn_mfma_f32_16x16x32_bf16(af[mi], bf[ni], acc[mi][ni], 0, 0, 0);
  };

  stage(0, 0);
  const int NKS = NI / 32;
  int ks = 0;
  for (; ks < NKS - 1; ks++) {
    stage((ks + 1) & 1, ks + 1);
    S_WAITCNT_VMCNT(4);
    wave_barrier();
    compute(ks & 1);
    wave_barrier();
  }
  S_WAITCNT_VMCNT(0);
  wave_barrier();
  compute(ks & 1);

  const int rh = lane >> 4;
#pragma unroll
  for (int mi = 0; mi < 4; mi++)
#pragma unroll
    for (int ni = 0; ni < 4; ni++)
#pragma unroll
      for (int j = 0; j < 4; j++) {
        int grow = rowbase + wr * 64 + mi * 16 + rh * 4 + j;
        if (grow < rowend) {
          int gcol = n0 + wc * 64 + ni * 16 + rl;
          y[(size_t)grow * HD + gcol] = f2bf(acc[mi][ni][j]);
        }
      }
}

// ---------------- combine: out[t] = w0*y[r0] + w1*y[r1] ----------------
__global__ void combine_kernel(const unsigned short* __restrict__ y,
                               const int2* __restrict__ tok2row,
                               const int4* __restrict__ tokinfo,
                               float* __restrict__ out) {
  int t = blockIdx.x, tid = threadIdx.x;
  int2 rr = tok2row[t];
  int4 info = tokinfo[t];
  float w0 = __int_as_float(info.z), w1 = __int_as_float(info.w);
  ushort8 a = ((const ushort8*)(y + (size_t)rr.x * HD))[tid];
  ushort8 b = ((const ushort8*)(y + (size_t)rr.y * HD))[tid];
  float4 o0, o1;
  o0.x = w0 * bf2f(a[0]) + w1 * bf2f(b[0]);
  o0.y = w0 * bf2f(a[1]) + w1 * bf2f(b[1]);
  o0.z = w0 * bf2f(a[2]) + w1 * bf2f(b[2]);
  o0.w = w0 * bf2f(a[3]) + w1 * bf2f(b[3]);
  o1.x = w0 * bf2f(a[4]) + w1 * bf2f(b[4]);
  o1.y = w0 * bf2f(a[5]) + w1 * bf2f(b[5]);
  o1.z = w0 * bf2f(a[6]) + w1 * bf2f(b[6]);
  o1.w = w0 * bf2f(a[7]) + w1 * bf2f(b[7]);
  float4* op = (float4*)(out + (size_t)t * HD + tid * 8);
  op[0] = o0; op[1] = o1;
}

// ---------------- launch ----------------
extern "C" void kernel_launch(void* const* d_in, const int* in_sizes, int n_in,
                              void* d_out, int out_size, void* d_ws, size_t ws_size,
                              hipStream_t stream) {
  const float* x  = (const float*)d_in[0];
  const float* Wr = (const float*)d_in[1];
  const float* Wg = (const float*)d_in[2];
  const float* Wu = (const float*)d_in[3];
  const float* Wd = (const float*)d_in[4];
  float* out = (float*)d_out;
  char* ws = (char*)d_ws;

  // ws layout (bytes)
  unsigned short* xbf = (unsigned short*)(ws);                 // 16,777,216
  unsigned short* Wgt = (unsigned short*)(ws + 16777216);      // 46,137,344
  unsigned short* Wut = (unsigned short*)(ws + 62914560);      // 46,137,344
  unsigned short* Wdt = (unsigned short*)(ws + 109051904);     // 46,137,344
  unsigned short* act = (unsigned short*)(ws + 155189248);     // 23,068,672
  // y aliases Wgt: gemm1 (last reader of Wgt) completes before gemm2 writes y.
  unsigned short* yb  = (unsigned short*)(ws + 16777216);      // 33,554,432
  int4*  tokinfo      = (int4*)(ws + 178257920);               // 65,536
  int*   row_tok      = (int*)(ws + 178323456);                // 32,768
  int2*  tok2row      = (int2*)(ws + 178356224);               // 32,768
  int*   cnt          = (int*)(ws + 178388992);                // 96

  hipMemsetAsync(cnt, 0, 96, stream);

  router_kernel<<<T_TOK / 4, 256, 0, stream>>>(x, Wr, out + (size_t)T_TOK * HD, xbf, tokinfo, cnt);
  offsets_kernel<<<1, 1, 0, stream>>>(cnt);
  scatter_kernel<<<T_TOK / 256, 256, 0, stream>>>(tokinfo, cnt, row_tok, tok2row);

  transpose_cvt_kernel<<<dim3(NI / 64, HD / 64, NE), 256, 0, stream>>>(Wg, Wgt, HD, NI);
  transpose_cvt_kernel<<<dim3(NI / 64, HD / 64, NE), 256, 0, stream>>>(Wu, Wut, HD, NI);
  transpose_cvt_kernel<<<dim3(HD / 64, NI / 64, NE), 256, 0, stream>>>(Wd, Wdt, NI, HD);

  gemm1_kernel<<<dim3(11, 32, NE), 256, 0, stream>>>(xbf, Wgt, Wut, act, row_tok, cnt);
  gemm2_kernel<<<dim3(16, 32, NE), 256, 0, stream>>>(act, Wdt, yb, cnt);
  combine_kernel<<<T_TOK, 256, 0, stream>>>(yb, tok2row, tokinfo, out);
}